// Round 7
// baseline (41.187 us; speedup 1.0000x reference)
//
#include <hip/hip_runtime.h>
#include <hip/hip_bf16.h>

// NF4 double-quant dequantize + x @ W^T   (MFMA, LDS-staged)
// x: [32][4096] f32 in memory (harness promotes fp16 inputs to f32 — pinned
//    by r1-vs-r5 error forensics).
// out: [32][14336] f32 in memory (harness reads fp16-typed outputs via the
//    float32 branch — pinned by r5/r6 bit-identical 2520 analysis).
// packed: [N/2] int32, one byte (two nibbles) per word; even k = low nibble.
// y[r,o] = sum_k x[r,k] * deq(W[o,k]),  deq = nib*cs - offset[b]*cs
// cs = (absmax[b]/code[b]) * (g_absmax[g]/g_code[g]),  b = elem/64, g = elem/256

#define OUT_D 14336
#define IN_D  4096
#define B_D   32
#define KC    256                 // k-chunk per LDS stage
#define OTILE 32                  // W rows per block
#define NCHUNK (IN_D / KC)        // 16
#define LSTRIDE 264               // bf16 elems per LDS row (256 + 8 pad)

typedef __attribute__((ext_vector_type(4))) float f32x4;
typedef __bf16 bf16x8 __attribute__((ext_vector_type(8)));
typedef __bf16 bf16x4 __attribute__((ext_vector_type(4)));
using u16 = unsigned short;

__global__ __launch_bounds__(256) void nf4_linear_kernel(
    const float* __restrict__ x,        // [32][4096] f32
    const int*  __restrict__ packed,    // [N/2] one byte value per int32
    const float* __restrict__ absmax,   // [NB]
    const float* __restrict__ code,     // [NB]
    const float* __restrict__ offset,   // [NB]
    const float* __restrict__ g_absmax, // [NG]
    const float* __restrict__ g_code,   // [NG]
    float* __restrict__ out)            // [32][14336] f32
{
    __shared__ u16 wlds[OTILE * LSTRIDE];
    __shared__ u16 xlds[B_D * LSTRIDE];

    const int t      = threadIdx.x;
    const int o_base = blockIdx.x * OTILE;

    // staging roles: 8 threads per W row, 32-elem (16-word) segment each
    const int wrow = t >> 3;        // 0..31
    const int wseg = t & 7;         // 0..7
    const int o    = o_base + wrow;

    // mfma roles: wave -> (m-half, n-half)
    const int wave   = t >> 6;
    const int lane   = t & 63;
    const int m_base = (wave & 1) * 16;
    const int n_base = (wave >> 1) * 16;
    const int frow   = lane & 15;        // own-row index for A/B frags
    const int kk     = (lane >> 4) * 8;  // k sub-offset

    f32x4 acc = {0.f, 0.f, 0.f, 0.f};

    for (int kc = 0; kc < NCHUNK; ++kc) {
        // ---- stage x chunk: 32 rows x 256 cols, f32 -> bf16 ----
        #pragma unroll
        for (int j = 0; j < 8; ++j) {
            int li = t + j * 256;            // 0..2047 float4 loads
            int xr = li >> 6;                // row 0..31 (64 float4 per row)
            int xc = (li & 63) * 4;          // col 0..252
            f32x4 v = *reinterpret_cast<const f32x4*>(x + xr * IN_D + kc * KC + xc);
            bf16x4 h;
            h[0] = (__bf16)v[0]; h[1] = (__bf16)v[1];
            h[2] = (__bf16)v[2]; h[3] = (__bf16)v[3];
            *reinterpret_cast<bf16x4*>(&xlds[xr * LSTRIDE + xc]) = h;
        }

        // ---- stage + dequant W chunk: 32 rows x 256 cols ----
        // this thread's 32 elems: k = kc*256 + wseg*32 .. +32 (inside ONE 64-block)
        const int bidx = o * 64 + kc * 4 + (wseg >> 1);
        const int gidx = o * 16 + kc;
        const float cs  = (absmax[bidx] / code[bidx]) * (g_absmax[gidx] / g_code[gidx]);
        const float noc = -offset[bidx] * cs;

        const int* psrc = packed + o * (IN_D / 2) + kc * (KC / 2) + wseg * 16;
        #pragma unroll
        for (int j = 0; j < 4; ++j) {
            bf16x8 r;
            #pragma unroll
            for (int wi = 0; wi < 4; ++wi) {
                int w = psrc[j * 4 + wi];
                float lo = (float)(w & 15);
                float hi = (float)((w >> 4) & 15);
                r[wi * 2]     = (__bf16)fmaf(lo, cs, noc);
                r[wi * 2 + 1] = (__bf16)fmaf(hi, cs, noc);
            }
            *reinterpret_cast<bf16x8*>(&wlds[wrow * LSTRIDE + wseg * 32 + j * 8]) = r;
        }
        __syncthreads();

        // ---- MFMA: wave computes 16x16 tile, 8 k-steps of 32 ----
        const u16* xrow_p = &xlds[(m_base + frow) * LSTRIDE + kk];
        const u16* wrow_p = &wlds[(n_base + frow) * LSTRIDE + kk];
        #pragma unroll
        for (int ks = 0; ks < KC / 32; ++ks) {
            bf16x8 a = *reinterpret_cast<const bf16x8*>(xrow_p + ks * 32);
            bf16x8 b = *reinterpret_cast<const bf16x8*>(wrow_p + ks * 32);
            acc = __builtin_amdgcn_mfma_f32_16x16x32_bf16(a, b, acc, 0, 0, 0);
        }
        __syncthreads();
    }

    // ---- epilogue: D col = lane&15 (out col), row = (lane>>4)*4 + i (batch) ----
    const int oc = o_base + n_base + frow;
    const int r0 = m_base + (lane >> 4) * 4;
    #pragma unroll
    for (int i = 0; i < 4; ++i) {
        out[(r0 + i) * OUT_D + oc] = acc[i];
    }
}

extern "C" void kernel_launch(void* const* d_in, const int* in_sizes, int n_in,
                              void* d_out, int out_size, void* d_ws, size_t ws_size,
                              hipStream_t stream) {
    // by-size identification (validated r5/r6: dict-order trio is correct;
    // by-size keeps us safe under any cross-size permutation)
    const void* px = nullptr;
    const void* ppk = nullptr;
    const void* trio[3] = {nullptr, nullptr, nullptr};
    const void* pair[2] = {nullptr, nullptr};
    int ntrio = 0, npair = 0;
    const int SZ_X   = B_D * IN_D;            // 131072
    const int SZ_PK  = OUT_D * (IN_D / 2);    // 29360128
    const int SZ_NB  = OUT_D * (IN_D / 64);   // 917504
    const int SZ_NG  = OUT_D * (IN_D / 256);  // 229376
    for (int i = 0; i < n_in; ++i) {
        int s = in_sizes[i];
        if (s == SZ_X) px = d_in[i];
        else if (s == SZ_PK) ppk = d_in[i];
        else if (s == SZ_NB) { if (ntrio < 3) trio[ntrio++] = d_in[i]; }
        else if (s == SZ_NG) { if (npair < 2) pair[npair++] = d_in[i]; }
    }
    if (!px || !ppk || ntrio != 3 || npair != 2) {
        px = d_in[0]; ppk = d_in[1];
        trio[0] = d_in[2]; trio[1] = d_in[3]; trio[2] = d_in[4];
        pair[0] = d_in[5]; pair[1] = d_in[6];
    }

    nf4_linear_kernel<<<dim3(OUT_D / OTILE), dim3(256), 0, stream>>>(
        (const float*)px, (const int*)ppk,
        (const float*)trio[0], (const float*)trio[1], (const float*)trio[2],
        (const float*)pair[0], (const float*)pair[1],
        (float*)d_out);
}